// Round 4
// baseline (2337.149 us; speedup 1.0000x reference)
//
#include <hip/hip_runtime.h>
#include <hip/hip_bf16.h>

typedef unsigned short ushort_t;

#define DEV __device__ __forceinline__

constexpr int Dd  = 64;
constexpr int VD  = 4525;
constexpr int VL  = 753;
constexpr int ND  = Dd * VD;     // 289600
constexpr int NLN = Dd * VL;     // 48192
constexpr int Hh  = 128;
constexpr int EMB = 10;
constexpr int TV  = 100;
constexpr int NH  = 8, HD = 16;
constexpr int L_ENC = 6, FF = 2048;
constexpr int GL  = 2;
constexpr int ED  = 32768, ET = 131072;
constexpr int KK  = 256;
constexpr int NCAND = (Dd - 1) * KK;       // 16128
constexpr int UCAP  = ET + NCAND;          // 147200 (worst-case |A ∪ B|)
constexpr int NCANON = 35;

DEV float bf(ushort_t u) { return __uint_as_float(((unsigned)u) << 16); }
DEV ushort_t f2bf(float f) {
    unsigned u = __float_as_uint(f);
    u += 0x7fffu + ((u >> 16) & 1u);
    return (ushort_t)(u >> 16);
}

// ---------------------------------------------------------------------------
// dtype probe: fp32 data has mantissa bit14 ~uniform; packed-bf16 data has the
// even element's exponent-MSB there (never set for |w| << 2). flag=1 -> fp32.
__global__ __launch_bounds__(64)
void k_probe(const unsigned* __restrict__ w, int* __restrict__ flag)
{
    int tid = threadIdx.x;
    int c = 0;
    #pragma unroll
    for (int i = 0; i < 16; i++) c += (w[tid * 16 + i] >> 14) & 1;
    #pragma unroll
    for (int o = 32; o; o >>= 1) c += __shfl_xor(c, o);
    if (tid == 0) *flag = (c > 256) ? 1 : 0;
}

// canonicalize all float tensors into one fp32 buffer
struct CanonDesc {
    const void* src[NCANON];
    int doff[NCANON];      // dst element offset (32B-aligned)
    int bend[NCANON];      // inclusive cumulative block count
    int n[NCANON];         // element count
};

__global__ __launch_bounds__(256)
void k_canon(CanonDesc cd, float* __restrict__ dst, const int* __restrict__ flag)
{
    int b = blockIdx.x;
    int t = 0;
    while (t < NCANON && b >= cd.bend[t]) t++;
    if (t >= NCANON) return;
    int bstart = (t == 0) ? 0 : cd.bend[t - 1];
    int i = (b - bstart) * 256 + threadIdx.x;
    if (i >= cd.n[t]) return;
    float v = (*flag) ? ((const float*)cd.src[t])[i]
                      : bf(((const ushort_t*)cd.src[t])[i]);
    dst[cd.doff[t] + i] = v;
}

// ---------------------------------------------------------------------------
// mark drug nodes: bit0 = is a took_dst (set A), bit1 = is a candidate (set B)
__global__ __launch_bounds__(256)
void k_mark(const int* __restrict__ took_dst, const int* __restrict__ cand,
            int* __restrict__ map)
{
    int g = blockIdx.x * 256 + threadIdx.x;
    if (g < ET) atomicOr(&map[took_dst[g]], 1);
    if (g < NCAND) {
        int d = g >> 8;                  // KK = 256
        atomicOr(&map[d * VD + cand[g]], 2);
    }
}

// assign compact slots; map[i] = (slot<<2)|flags ; build ulist (node ids), blist (slots)
__global__ __launch_bounds__(256)
void k_assign(int* __restrict__ map, int* __restrict__ ulist, int* __restrict__ blist,
              int* __restrict__ nUB)
{
    int g = blockIdx.x * 256 + threadIdx.x;
    if (g >= ND) return;
    int m = map[g];
    if (m) {
        int s = atomicAdd(&nUB[0], 1);
        ulist[s] = g;
        map[g] = (s << 2) | m;
        if (m & 2) {
            int b = atomicAdd(&nUB[1], 1);
            blist[b] = s;
        }
    }
}

// edge-degree counts
__global__ __launch_bounds__(256)
void k_counts(const int* __restrict__ did_dst, const int* __restrict__ did_src,
              const int* __restrict__ took_dst, const int* __restrict__ took_src,
              const int* __restrict__ map,
              int* __restrict__ cnt_ld, int* __restrict__ cnt_a1,
              int* __restrict__ cnt_dc, int* __restrict__ cnt_a2)
{
    int g = blockIdx.x * 256 + threadIdx.x;
    if (g < ED) {
        atomicAdd(&cnt_ld[did_dst[g]], 1);
        atomicAdd(&cnt_a1[did_src[g]], 1);
    }
    if (g < ET) {
        atomicAdd(&cnt_dc[map[took_dst[g]] >> 2], 1);
        atomicAdd(&cnt_a2[took_src[g]], 1);
    }
}

// ---------------------------------------------------------------------------
// embedding + align projection (all weights canonical fp32).
template<int NID, int NTOK, int NF, bool BF16OUT, bool INDIRECT>
__global__ __launch_bounds__(64)
void k_embed(void* __restrict__ out, int n_static, const int* __restrict__ n_dyn,
             const int* __restrict__ ulist,
             const int* __restrict__ id_idx, const float* __restrict__ id_emb,
             const int* __restrict__ tokens, const float* __restrict__ tok_emb,
             const float* __restrict__ floats_, const float* __restrict__ float_w,
             const float* __restrict__ alignf)
{
    constexpr int L = (NID + NTOK + 1) * EMB;
    int slot = blockIdx.x * 64 + threadIdx.x;
    int n = INDIRECT ? *n_dyn : n_static;
    if (slot >= n) return;
    int node = INDIRECT ? ulist[slot] : slot;

    float vec[L];
    int p = 0;
    if constexpr (NID != 0) {
        const float* pe = id_emb + (size_t)id_idx[node] * EMB;
        #pragma unroll
        for (int e = 0; e < EMB; e++) vec[p++] = pe[e];
    }
    #pragma unroll
    for (int t = 0; t < NTOK; t++) {
        const float* pe = tok_emb + ((size_t)t * TV + tokens[node * NTOK + t]) * EMB;
        #pragma unroll
        for (int e = 0; e < EMB; e++) vec[p++] = pe[e];
    }
    {
        float fv[NF];
        #pragma unroll
        for (int f = 0; f < NF; f++) fv[f] = floats_[node * NF + f];
        #pragma unroll
        for (int e = 0; e < EMB; e++) {
            float a = 0.f;
            #pragma unroll
            for (int f = 0; f < NF; f++) a = fmaf(fv[f], float_w[f * EMB + e], a);
            vec[p++] = a;
        }
    }

    #pragma unroll 1
    for (int j = 0; j < Hh; j += 4) {
        float a0 = 0.f, a1 = 0.f, a2 = 0.f, a3 = 0.f;
        #pragma unroll
        for (int i = 0; i < L; i++) {
            const float* w = alignf + i * Hh + j;   // uniform -> scalar loads
            a0 = fmaf(vec[i], w[0], a0);
            a1 = fmaf(vec[i], w[1], a1);
            a2 = fmaf(vec[i], w[2], a2);
            a3 = fmaf(vec[i], w[3], a3);
        }
        if constexpr (BF16OUT) {
            unsigned lo = (unsigned)f2bf(a0) | ((unsigned)f2bf(a1) << 16);
            unsigned hi = (unsigned)f2bf(a2) | ((unsigned)f2bf(a3) << 16);
            uint2 v; v.x = lo; v.y = hi;
            *reinterpret_cast<uint2*>((ushort_t*)out + (size_t)slot * Hh + j) = v;
        } else {
            float4 r4; r4.x = a0; r4.y = a1; r4.z = a2; r4.w = a3;
            *reinterpret_cast<float4*>((float*)out + (size_t)slot * Hh + j) = r4;
        }
    }
}

// ---------------------------------------------------------------------------
// did-edge scatter: S_l[dst] += x_a[src]+e (layer1 only) ; S_a1[src] += x_l[dst]+e
__global__ __launch_bounds__(256)
void k_scatter_did(const int* __restrict__ src, const int* __restrict__ dst,
                   const ushort_t* __restrict__ efeat,
                   const float* __restrict__ x_a, const ushort_t* __restrict__ x_l,
                   float* __restrict__ S_l, float* __restrict__ S_a1,
                   int epb, int write_main)
{
    __shared__ float acc[Dd * Hh];
    int tid = threadIdx.x;
    for (int i = tid; i < Dd * Hh; i += 256) acc[i] = 0.f;
    __syncthreads();
    int j = tid & 127;
    int e0 = blockIdx.x * epb;
    for (int e = e0 + (tid >> 7); e < e0 + epb; e += 2) {
        int s = src[e], d = dst[e];
        float ev = bf(efeat[(size_t)e * Hh + j]);
        if (write_main)
            unsafeAtomicAdd(&S_l[(size_t)d * Hh + j], x_a[s * Hh + j] + ev);
        atomicAdd(&acc[s * Hh + j], bf(x_l[(size_t)d * Hh + j]) + ev);
    }
    __syncthreads();
    for (int i = tid; i < Dd * Hh; i += 256) unsafeAtomicAdd(&S_a1[i], acc[i]);
}

// took-edge scatter: S_dc[slot(dst)] += x_a[src]+e (layer2: only B rows) ;
//                    S_a2[src] += x_dc[slot(dst)]+e
__global__ __launch_bounds__(256)
void k_scatter_took(const int* __restrict__ src, const int* __restrict__ dst,
                    const ushort_t* __restrict__ efeat,
                    const float* __restrict__ x_a, const ushort_t* __restrict__ x_dc,
                    const int* __restrict__ map,
                    float* __restrict__ S_dc, float* __restrict__ S_a2,
                    int epb, int layer2)
{
    __shared__ float acc[Dd * Hh];
    int tid = threadIdx.x;
    for (int i = tid; i < Dd * Hh; i += 256) acc[i] = 0.f;
    __syncthreads();
    int j = tid & 127;
    int e0 = blockIdx.x * epb;
    for (int e = e0 + (tid >> 7); e < e0 + epb; e += 2) {
        int s = src[e], d = dst[e];
        int mf = map[d];
        int slot = mf >> 2;
        float ev = bf(efeat[(size_t)e * Hh + j]);
        if (!layer2 || (mf & 2))
            unsafeAtomicAdd(&S_dc[(size_t)slot * Hh + j], x_a[s * Hh + j] + ev);
        atomicAdd(&acc[s * Hh + j], bf(x_dc[(size_t)slot * Hh + j]) + ev);
    }
    __syncthreads();
    for (int i = tid; i < Dd * Hh; i += 256) unsafeAtomicAdd(&S_a2[i], acc[i]);
}

// ---------------------------------------------------------------------------
// Fused GNN update (bf16 storage, fp32 math, fp32 weights):
//   X[r,:] = relu?( X[r,:]@Wself + (S[r,:]/max(c,1))@Wmsg )
template<bool INDIRECT>
__global__ __launch_bounds__(128)
void k_update(ushort_t* __restrict__ X, const float* __restrict__ S,
              const int* __restrict__ cnt, const int* __restrict__ rows_list,
              const int* __restrict__ n_dyn, int n_static,
              const float* __restrict__ Wself, const float* __restrict__ Wmsg,
              int do_relu)
{
    __shared__ float Xs[32 * 130];
    __shared__ float Ss[32 * 130];
    __shared__ float inv[32];
    __shared__ int rowid[32];
    int tid = threadIdx.x;
    int r0 = blockIdx.x * 32;
    int n = n_dyn ? *n_dyn : n_static;
    if (tid < 32) {
        int row = r0 + tid;
        int rr = -1;
        if (row < n) rr = INDIRECT ? rows_list[row] : row;
        rowid[tid] = rr;
        inv[tid] = (rr >= 0) ? 1.0f / fmaxf((float)cnt[rr], 1.0f) : 0.f;
    }
    __syncthreads();
    for (int idx = tid; idx < 32 * 128; idx += 128) {
        int r = idx >> 7, c = idx & 127;
        int rr = rowid[r];
        float xv = 0.f, sv = 0.f;
        if (rr >= 0) {
            xv = bf(X[(size_t)rr * Hh + c]);
            sv = S[(size_t)rr * Hh + c] * inv[r];
        }
        Xs[r * 130 + c] = xv;
        Ss[r * 130 + c] = sv;
    }
    __syncthreads();

    int jg = tid & 15, rg = tid >> 4;
    int j0 = jg * 8, rr0 = rg * 4;
    float acc[4][8];
    #pragma unroll
    for (int i = 0; i < 4; i++)
        #pragma unroll
        for (int c = 0; c < 8; c++) acc[i][c] = 0.f;

    #pragma unroll 2
    for (int k = 0; k < 128; k++) {
        float xv[4], sv[4];
        #pragma unroll
        for (int i = 0; i < 4; i++) {
            xv[i] = Xs[(rr0 + i) * 130 + k];
            sv[i] = Ss[(rr0 + i) * 130 + k];
        }
        const float* w1p = Wself + k * Hh + j0;
        const float* w2p = Wmsg  + k * Hh + j0;
        float4 w1a = *reinterpret_cast<const float4*>(w1p);
        float4 w1b = *reinterpret_cast<const float4*>(w1p + 4);
        float4 w2a = *reinterpret_cast<const float4*>(w2p);
        float4 w2b = *reinterpret_cast<const float4*>(w2p + 4);
        float w1[8] = {w1a.x, w1a.y, w1a.z, w1a.w, w1b.x, w1b.y, w1b.z, w1b.w};
        float w2[8] = {w2a.x, w2a.y, w2a.z, w2a.w, w2b.x, w2b.y, w2b.z, w2b.w};
        #pragma unroll
        for (int i = 0; i < 4; i++)
            #pragma unroll
            for (int c = 0; c < 8; c++)
                acc[i][c] = fmaf(xv[i], w1[c], fmaf(sv[i], w2[c], acc[i][c]));
    }

    #pragma unroll
    for (int i = 0; i < 4; i++) {
        int rr = rowid[rr0 + i];
        if (rr < 0) continue;
        float o[8];
        #pragma unroll
        for (int c = 0; c < 8; c++) {
            o[c] = acc[i][c];
            if (do_relu) o[c] = fmaxf(o[c], 0.f);
        }
        uint4 v;
        v.x = (unsigned)f2bf(o[0]) | ((unsigned)f2bf(o[1]) << 16);
        v.y = (unsigned)f2bf(o[2]) | ((unsigned)f2bf(o[3]) << 16);
        v.z = (unsigned)f2bf(o[4]) | ((unsigned)f2bf(o[5]) << 16);
        v.w = (unsigned)f2bf(o[6]) | ((unsigned)f2bf(o[7]) << 16);
        *reinterpret_cast<uint4*>(X + (size_t)rr * Hh + j0) = v;
    }
}

// ---------------------------------------------------------------------------
// x_a update (f32): x_a = relu?( x_a@Ws + (S_a1/c1)@Wm1 + (S_a2/c2)@Wm2 )
__global__ __launch_bounds__(128)
void k_xa(float* __restrict__ x_a, const float* __restrict__ S_a1, const float* __restrict__ S_a2,
          const int* __restrict__ c1, const int* __restrict__ c2,
          const float* __restrict__ Wself, const float* __restrict__ Wm1,
          const float* __restrict__ Wm2, int do_relu)
{
    int r = blockIdx.x, tid = threadIdx.x;
    __shared__ float xr[128], a1[128], a2[128];
    float i1 = 1.f / fmaxf((float)c1[r], 1.f);
    float i2 = 1.f / fmaxf((float)c2[r], 1.f);
    xr[tid] = x_a[r * Hh + tid];
    a1[tid] = S_a1[r * Hh + tid] * i1;
    a2[tid] = S_a2[r * Hh + tid] * i2;
    __syncthreads();
    float acc = 0.f;
    for (int k = 0; k < 128; k++) {
        acc = fmaf(xr[k], Wself[k * Hh + tid], acc);
        acc = fmaf(a1[k], Wm1[k * Hh + tid], acc);
        acc = fmaf(a2[k], Wm2[k * Hh + tid], acc);
    }
    if (do_relu) acc = fmaxf(acc, 0.f);
    x_a[r * Hh + tid] = acc;
}

// ---------------------------------------------------------------------------
// Transformer pieces (D=64, H=128), all fp32.
__global__ __launch_bounds__(128)
void k_qkv(const float* __restrict__ h, float* __restrict__ qkv,
           const float* __restrict__ W, const float* __restrict__ b)
{
    int r = blockIdx.x, tid = threadIdx.x;
    __shared__ float hr[128];
    hr[tid] = h[r * Hh + tid];
    __syncthreads();
    #pragma unroll
    for (int c0 = 0; c0 < 3; c0++) {
        int c = c0 * 128 + tid;
        float acc = b[c];
        for (int k = 0; k < 128; k++) acc = fmaf(hr[k], W[k * 384 + c], acc);
        qkv[r * 384 + c] = acc;
    }
}

__global__ __launch_bounds__(64)
void k_attn(const float* __restrict__ qkv, float* __restrict__ attn_o)
{
    int hh = blockIdx.x, q = blockIdx.y;
    int lane = threadIdx.x;
    const float* qv = qkv + q * 384 + hh * HD;
    const float* kv = qkv + lane * 384 + 128 + hh * HD;
    float s = 0.f;
    #pragma unroll
    for (int d2 = 0; d2 < HD; d2++) s = fmaf(qv[d2], kv[d2], s);
    s = s * 0.25f + (lane <= q ? 0.f : -1e9f);
    float m = s;
    #pragma unroll
    for (int o = 32; o; o >>= 1) m = fmaxf(m, __shfl_xor(m, o));
    float e = __expf(s - m);
    float tot = e;
    #pragma unroll
    for (int o = 32; o; o >>= 1) tot += __shfl_xor(tot, o);
    float att = e / tot;
    __shared__ float satt[64];
    satt[lane] = att;
    __syncthreads();
    if (lane < HD) {
        float o = 0.f;
        for (int k2 = 0; k2 < Dd; k2++) o = fmaf(satt[k2], qkv[k2 * 384 + 256 + hh * HD + lane], o);
        attn_o[q * Hh + hh * HD + lane] = o;
    }
}

DEV float blocksum128(float v, float* red)
{
    #pragma unroll
    for (int o = 32; o; o >>= 1) v += __shfl_xor(v, o);
    int wid = threadIdx.x >> 6;
    __syncthreads();
    if ((threadIdx.x & 63) == 0) red[wid] = v;
    __syncthreads();
    return red[0] + red[1];
}

__global__ __launch_bounds__(128)
void k_outln(const float* __restrict__ attn_o, float* __restrict__ h,
             const float* __restrict__ Wout, const float* __restrict__ bout,
             const float* __restrict__ ln)
{
    int r = blockIdx.x, tid = threadIdx.x;
    __shared__ float ar[128];
    __shared__ float red[2];
    ar[tid] = attn_o[r * Hh + tid];
    __syncthreads();
    float acc = bout[tid];
    for (int k = 0; k < 128; k++) acc = fmaf(ar[k], Wout[k * Hh + tid], acc);
    float x = h[r * Hh + tid] + acc;
    float mu = blocksum128(x, red) * (1.f / 128.f);
    float dx = x - mu;
    float var = blocksum128(dx * dx, red) * (1.f / 128.f);
    float y = ln[tid] * dx * (1.f / sqrtf(var + 1e-5f)) + ln[128 + tid];
    h[r * Hh + tid] = y;
}

__global__ __launch_bounds__(256)
void k_ff1(const float* __restrict__ h, float* __restrict__ fbuf,
           const float* __restrict__ W1, const float* __restrict__ b1)
{
    int r = blockIdx.x, tid = threadIdx.x;
    int c = blockIdx.y * 256 + tid;
    __shared__ float hr[128];
    if (tid < 128) hr[tid] = h[r * Hh + tid];
    __syncthreads();
    float acc = b1[c];
    for (int k = 0; k < 128; k++) acc = fmaf(hr[k], W1[(size_t)k * FF + c], acc);
    fbuf[(size_t)r * FF + c] = fmaxf(acc, 0.f);
}

__global__ __launch_bounds__(128)
void k_ff2p(const float* __restrict__ fbuf, float* __restrict__ part,
            const float* __restrict__ W2)
{
    int r = blockIdx.x, pi = blockIdx.y, tid = threadIdx.x;
    int kc = pi * 128;
    float acc = 0.f;
    for (int k = kc; k < kc + 128; k++)
        acc = fmaf(fbuf[(size_t)r * FF + k], W2[(size_t)k * Hh + tid], acc);
    part[(size_t)(r * 16 + pi) * Hh + tid] = acc;
}

__global__ __launch_bounds__(128)
void k_ln2(float* __restrict__ h, const float* __restrict__ part,
           const float* __restrict__ b2, const float* __restrict__ ln)
{
    int r = blockIdx.x, tid = threadIdx.x;
    __shared__ float red[2];
    float acc = b2[tid];
    #pragma unroll
    for (int pi = 0; pi < 16; pi++) acc += part[(size_t)(r * 16 + pi) * Hh + tid];
    float x = h[r * Hh + tid] + acc;
    float mu = blocksum128(x, red) * (1.f / 128.f);
    float dx = x - mu;
    float var = blocksum128(dx * dx, red) * (1.f / 128.f);
    float y = ln[tid] * dx * (1.f / sqrtf(var + 1e-5f)) + ln[128 + tid];
    h[r * Hh + tid] = y;
}

// ---------------------------------------------------------------------------
// logits[d,k] = sum_h x_dc[slot(d*VD+cand[d,k]), h] * h[d,h] * lp_w[h]
// OUTPUT IS FP32 (reference returns float32 logits).
__global__ __launch_bounds__(256)
void k_logits(const ushort_t* __restrict__ x_dc, const int* __restrict__ map,
              const float* __restrict__ h, const float* __restrict__ lp,
              const int* __restrict__ cand, float* __restrict__ out)
{
    int d = blockIdx.x;
    int tid = threadIdx.x, lane = tid & 63, w = tid >> 6;
    __shared__ float wv[128];
    if (tid < 128) wv[tid] = h[d * Hh + tid] * lp[tid];
    __syncthreads();
    for (int k = w; k < KK; k += 4) {
        int slot = map[d * VD + cand[d * KK + k]] >> 2;
        const ushort_t* row = x_dc + (size_t)slot * Hh;
        float v = bf(row[lane]) * wv[lane] + bf(row[lane + 64]) * wv[lane + 64];
        #pragma unroll
        for (int o = 32; o; o >>= 1) v += __shfl_xor(v, o);
        if (lane == 0) out[d * KK + k] = v;
    }
}

// ---------------------------------------------------------------------------
extern "C" void kernel_launch(void* const* d_in, const int* in_sizes, int n_in,
                              void* d_out, int out_size, void* d_ws, size_t ws_size,
                              hipStream_t stream)
{
    (void)in_sizes; (void)n_in; (void)out_size; (void)ws_size;

    const int* drug_tokens  = (const int*)d_in[0];
    const int* drug_node_id = (const int*)d_in[1];
    const int* lab_tokens   = (const int*)d_in[3];
    const int* lab_node_id  = (const int*)d_in[4];
    const int* adm_tokens   = (const int*)d_in[6];
    const int* did_tokens   = (const int*)d_in[8];
    const int* did_src      = (const int*)d_in[10];
    const int* did_dst      = (const int*)d_in[11];
    const int* took_tokens  = (const int*)d_in[12];
    const int* took_src     = (const int*)d_in[14];
    const int* took_dst     = (const int*)d_in[15];
    const int* cand_idx     = (const int*)d_in[16];

    // float tensors to canonicalize (d_in index, element count)
    const int cidx[NCANON] = {2,5,7,9,13, 17,18,19,20,21,22,23, 24,25,26,27,28,
                              29,30,31,32,33, 34,35, 36,37,38,39,40,41,42,43,44,45,46};
    const int cn[NCANON] = {
        ND*2, NLN*1, Dd*3, ED*2, ET*1,
        VD*EMB, VL*EMB, 3*TV*EMB, 2*TV*EMB, 4*TV*EMB, 2*TV*EMB, 2*TV*EMB,
        2*EMB, 1*EMB, 3*EMB, 2*EMB, 1*EMB,
        5*EMB*Hh, 4*EMB*Hh, 5*EMB*Hh, 3*EMB*Hh, 3*EMB*Hh,
        GL*4*Hh*Hh, GL*3*Hh*Hh,
        L_ENC*Hh*3*Hh, L_ENC*3*Hh, L_ENC*Hh*Hh, L_ENC*Hh, L_ENC*2*Hh,
        L_ENC*Hh*FF, L_ENC*FF, L_ENC*FF*Hh, L_ENC*Hh, L_ENC*2*Hh, Hh
    };
    CanonDesc cd;
    int eoff[NCANON + 1];
    int btot = 0;
    {
        int e = 0;
        for (int t = 0; t < NCANON; t++) {
            cd.src[t] = d_in[cidx[t]];
            cd.n[t] = cn[t];
            eoff[t] = e;
            cd.doff[t] = e;
            e = (e + cn[t] + 7) & ~7;          // 32B-align each tensor
            btot += (cn[t] + 255) / 256;
            cd.bend[t] = btot;
        }
        eoff[NCANON] = e;
    }

    // ---- workspace carve ----
    char* p = (char*)d_ws;
    auto alloc_f = [&](size_t n) -> float*    { float* r = (float*)p;    p += n * sizeof(float); return r; };
    auto alloc_h = [&](size_t n) -> ushort_t* { ushort_t* r = (ushort_t*)p; p += n * sizeof(ushort_t); return r; };
    auto alloc_i = [&](size_t n) -> int*      { int* r = (int*)p;        p += n * sizeof(int); return r; };

    float* S_dc  = alloc_f((size_t)UCAP * Hh);   // 75.4 MB (memset start)
    float* S_a1  = alloc_f((size_t)Dd * Hh);
    float* S_a2  = alloc_f((size_t)Dd * Hh);
    float* S_l   = alloc_f((size_t)NLN * Hh);    // 24.7 MB
    int*   map    = alloc_i(ND);                 // zero-once block start
    int*   cnt_dc = alloc_i(UCAP);
    int*   cnt_ld = alloc_i(NLN);
    int*   cnt_a1 = alloc_i(64);
    int*   cnt_a2 = alloc_i(64);
    int*   nUB    = alloc_i(8);
    int*      ulist  = alloc_i(UCAP);
    int*      blist  = alloc_i(NCAND);
    ushort_t* x_dc   = alloc_h((size_t)UCAP * Hh);   // 37.7 MB bf16
    ushort_t* x_l    = alloc_h((size_t)NLN * Hh);    // 12.3 MB bf16
    float*    x_a    = alloc_f((size_t)Dd * Hh);
    ushort_t* e_did  = alloc_h((size_t)ED * Hh);     // 8.4 MB bf16
    ushort_t* e_took = alloc_h((size_t)ET * Hh);     // 33.6 MB bf16
    float*    qkvb   = alloc_f((size_t)Dd * 384);
    float*    attn_o = alloc_f((size_t)Dd * Hh);
    float*    fbuf   = alloc_f((size_t)Dd * FF);
    float*    part   = alloc_f((size_t)Dd * 16 * Hh);
    float*    cf     = alloc_f((size_t)eoff[NCANON]); // ~18.8 MB canonical fp32
    int*      dflag  = alloc_i(8);

    // canonical pointers
    const float* c_drug_floats  = cf + eoff[0];
    const float* c_lab_floats   = cf + eoff[1];
    const float* c_adm_floats   = cf + eoff[2];
    const float* c_did_floats   = cf + eoff[3];
    const float* c_took_floats  = cf + eoff[4];
    const float* c_drug_id_emb  = cf + eoff[5];
    const float* c_lab_id_emb   = cf + eoff[6];
    const float* c_drug_tok_emb = cf + eoff[7];
    const float* c_lab_tok_emb  = cf + eoff[8];
    const float* c_adm_tok_emb  = cf + eoff[9];
    const float* c_did_tok_emb  = cf + eoff[10];
    const float* c_took_tok_emb = cf + eoff[11];
    const float* c_drug_float_w = cf + eoff[12];
    const float* c_lab_float_w  = cf + eoff[13];
    const float* c_adm_float_w  = cf + eoff[14];
    const float* c_did_float_w  = cf + eoff[15];
    const float* c_took_float_w = cf + eoff[16];
    const float* c_drug_align   = cf + eoff[17];
    const float* c_lab_align    = cf + eoff[18];
    const float* c_adm_align    = cf + eoff[19];
    const float* c_did_align    = cf + eoff[20];
    const float* c_took_align   = cf + eoff[21];
    const float* c_gnn_msg      = cf + eoff[22];
    const float* c_gnn_self     = cf + eoff[23];
    const float* c_qkv_w        = cf + eoff[24];
    const float* c_qkv_b        = cf + eoff[25];
    const float* c_out_w        = cf + eoff[26];
    const float* c_out_b        = cf + eoff[27];
    const float* c_ln1          = cf + eoff[28];
    const float* c_ff1_w        = cf + eoff[29];
    const float* c_ff1_b        = cf + eoff[30];
    const float* c_ff2_w        = cf + eoff[31];
    const float* c_ff2_b        = cf + eoff[32];
    const float* c_ln2          = cf + eoff[33];
    const float* c_lp_w         = cf + eoff[34];

    // ---- dtype probe + canonicalization ----
    k_probe<<<1, 64, 0, stream>>>((const unsigned*)d_in[41], dflag);
    k_canon<<<btot, 256, 0, stream>>>(cd, cf, dflag);

    // ---- build node map / counts ----
    hipMemsetAsync(map, 0, (size_t)(ND + UCAP + NLN + 64 + 64 + 8) * sizeof(int), stream);
    k_mark<<<ET / 256, 256, 0, stream>>>(took_dst, cand_idx, map);
    k_assign<<<(ND + 255) / 256, 256, 0, stream>>>(map, ulist, blist, nUB);
    k_counts<<<ET / 256, 256, 0, stream>>>(did_dst, did_src, took_dst, took_src, map,
                                           cnt_ld, cnt_a1, cnt_dc, cnt_a2);

    // ---- embeddings ----
    k_embed<1,3,2,true,true><<<UCAP / 64, 64, 0, stream>>>(x_dc, 0, nUB, ulist,
        drug_node_id, c_drug_id_emb, drug_tokens, c_drug_tok_emb, c_drug_floats, c_drug_float_w, c_drug_align);
    k_embed<1,2,1,true,false><<<NLN / 64, 64, 0, stream>>>(x_l, NLN, nullptr, nullptr,
        lab_node_id, c_lab_id_emb, lab_tokens, c_lab_tok_emb, c_lab_floats, c_lab_float_w, c_lab_align);
    k_embed<0,4,3,false,false><<<1, 64, 0, stream>>>(x_a, Dd, nullptr, nullptr,
        nullptr, nullptr, adm_tokens, c_adm_tok_emb, c_adm_floats, c_adm_float_w, c_adm_align);
    k_embed<0,2,2,true,false><<<ED / 64, 64, 0, stream>>>(e_did, ED, nullptr, nullptr,
        nullptr, nullptr, did_tokens, c_did_tok_emb, c_did_floats, c_did_float_w, c_did_align);
    k_embed<0,2,1,true,false><<<ET / 64, 64, 0, stream>>>(e_took, ET, nullptr, nullptr,
        nullptr, nullptr, took_tokens, c_took_tok_emb, c_took_floats, c_took_float_w, c_took_align);

    const size_t HH = (size_t)Hh * Hh;

    // ---- GNN layer 1 (relu) ----
    hipMemsetAsync(S_dc, 0, ((size_t)UCAP * Hh + 2 * Dd * Hh + (size_t)NLN * Hh) * sizeof(float), stream);
    k_scatter_did<<<64, 256, 0, stream>>>(did_src, did_dst, e_did, x_a, x_l, S_l, S_a1, ED / 64, 1);
    k_scatter_took<<<256, 256, 0, stream>>>(took_src, took_dst, e_took, x_a, x_dc, map, S_dc, S_a2, ET / 256, 0);
    k_xa<<<Dd, 128, 0, stream>>>(x_a, S_a1, S_a2, cnt_a1, cnt_a2,
                                 c_gnn_self + 0 * HH, c_gnn_msg + 2 * HH, c_gnn_msg + 3 * HH, 1);
    k_update<false><<<UCAP / 32, 128, 0, stream>>>(x_dc, S_dc, cnt_dc, nullptr, nUB, 0,
                                                   c_gnn_self + 1 * HH, c_gnn_msg + 1 * HH, 1);
    k_update<false><<<NLN / 32, 128, 0, stream>>>(x_l, S_l, cnt_ld, nullptr, nullptr, NLN,
                                                  c_gnn_self + 2 * HH, c_gnn_msg + 0 * HH, 1);

    // ---- GNN layer 2 (no relu; x_l update & S_l scatter dead; x_d over B only) ----
    const float* Ws1 = c_gnn_self + 3 * HH;
    const float* Wm1 = c_gnn_msg + 4 * HH;
    hipMemsetAsync(S_dc, 0, ((size_t)UCAP * Hh + 2 * Dd * Hh) * sizeof(float), stream);
    k_scatter_did<<<64, 256, 0, stream>>>(did_src, did_dst, e_did, x_a, x_l, S_l, S_a1, ED / 64, 0);
    k_scatter_took<<<256, 256, 0, stream>>>(took_src, took_dst, e_took, x_a, x_dc, map, S_dc, S_a2, ET / 256, 1);
    k_xa<<<Dd, 128, 0, stream>>>(x_a, S_a1, S_a2, cnt_a1, cnt_a2,
                                 Ws1 + 0 * HH, Wm1 + 2 * HH, Wm1 + 3 * HH, 0);
    k_update<true><<<NCAND / 32, 128, 0, stream>>>(x_dc, S_dc, cnt_dc, blist, nUB + 1, 0,
                                                   Ws1 + 1 * HH, Wm1 + 1 * HH, 0);

    // ---- transformer encoder on x_a ----
    for (int i = 0; i < L_ENC; i++) {
        k_qkv<<<Dd, 128, 0, stream>>>(x_a, qkvb, c_qkv_w + (size_t)i * Hh * 384, c_qkv_b + (size_t)i * 384);
        k_attn<<<dim3(NH, Dd), 64, 0, stream>>>(qkvb, attn_o);
        k_outln<<<Dd, 128, 0, stream>>>(attn_o, x_a, c_out_w + (size_t)i * HH,
                                        c_out_b + (size_t)i * Hh, c_ln1 + (size_t)i * 2 * Hh);
        k_ff1<<<dim3(Dd, FF / 256), 256, 0, stream>>>(x_a, fbuf, c_ff1_w + (size_t)i * Hh * FF,
                                                      c_ff1_b + (size_t)i * FF);
        k_ff2p<<<dim3(Dd, FF / 128), 128, 0, stream>>>(fbuf, part, c_ff2_w + (size_t)i * FF * Hh);
        k_ln2<<<Dd, 128, 0, stream>>>(x_a, part, c_ff2_b + (size_t)i * Hh, c_ln2 + (size_t)i * 2 * Hh);
    }

    // ---- logits ----
    k_logits<<<Dd - 1, 256, 0, stream>>>(x_dc, map, x_a, c_lp_w, cand_idx, (float*)d_out);
}